// Round 1
// baseline (2196.834 us; speedup 1.0000x reference)
//
#include <hip/hip_runtime.h>
#include <cstddef>
#include <cstdint>

// Problem constants
constexpr int B  = 8;
constexpr int L  = 1024;
constexpr int D  = 768;
constexpr int DI = 1536;
constexpr int DS = 16;
constexpr int NL = 2;
constexpr float DECAY   = 0.9f;
constexpr float INSCALE = 0.1f;
constexpr float LN_EPS  = 1e-5f;

__device__ __forceinline__ float siluf(float v) { return v / (1.0f + expf(-v)); }

// ---------------- copy x -> buf_x ----------------
__global__ void copy_f4(const float4* __restrict__ src, float4* __restrict__ dst, int n4) {
  int i = blockIdx.x * blockDim.x + threadIdx.x;
  if (i < n4) dst[i] = src[i];
}

// ---------------- classic tiled SGEMM ----------------
// C[M,N] = A[M,K] @ W[K,N]  (+= if ACCUM). All row-major. M,N,K divisible by tiles.
template<int BM, int BN, int BK, int TM, int TN, bool ACCUM>
__global__ __launch_bounds__(256) void sgemm(const float* __restrict__ A,
                                             const float* __restrict__ W,
                                             float* __restrict__ C,
                                             int M, int N, int K) {
  __shared__ float As[BK][BM];
  __shared__ float Bs[BK][BN];
  const int tid = threadIdx.x;
  const int bm = blockIdx.y * BM;
  const int bn = blockIdx.x * BN;
  const int tx = tid % (BN / TN);
  const int ty = tid / (BN / TN);

  float acc[TM][TN];
#pragma unroll
  for (int i = 0; i < TM; ++i)
#pragma unroll
    for (int j = 0; j < TN; ++j) acc[i][j] = 0.f;

  for (int k0 = 0; k0 < K; k0 += BK) {
    // A tile: BM x BK, stored transposed into As[BK][BM]
    for (int ch = tid; ch < BM * BK / 4; ch += 256) {
      int r = (ch * 4) / BK;
      int c = (ch * 4) % BK;
      float4 v = *(const float4*)&A[(size_t)(bm + r) * K + k0 + c];
      As[c + 0][r] = v.x; As[c + 1][r] = v.y;
      As[c + 2][r] = v.z; As[c + 3][r] = v.w;
    }
    // B tile: BK x BN
    for (int ch = tid; ch < BK * BN / 4; ch += 256) {
      int r = (ch * 4) / BN;
      int c = (ch * 4) % BN;
      *(float4*)&Bs[r][c] = *(const float4*)&W[(size_t)(k0 + r) * N + bn + c];
    }
    __syncthreads();
#pragma unroll
    for (int kk = 0; kk < BK; ++kk) {
      float a[TM], b[TN];
#pragma unroll
      for (int i = 0; i < TM; ++i) a[i] = As[kk][ty * TM + i];
#pragma unroll
      for (int j = 0; j < TN; ++j) b[j] = Bs[kk][tx * TN + j];
#pragma unroll
      for (int i = 0; i < TM; ++i)
#pragma unroll
        for (int j = 0; j < TN; ++j) acc[i][j] += a[i] * b[j];
    }
    __syncthreads();
  }

#pragma unroll
  for (int i = 0; i < TM; ++i) {
    size_t rowoff = (size_t)(bm + ty * TM + i) * N + bn + tx * TN;
#pragma unroll
    for (int j = 0; j < TN; j += 4) {
      float4 v = make_float4(acc[i][j], acc[i][j + 1], acc[i][j + 2], acc[i][j + 3]);
      if (ACCUM) {
        float4 o = *(float4*)&C[rowoff + j];
        v.x += o.x; v.y += o.y; v.z += o.z; v.w += o.w;
      }
      *(float4*)&C[rowoff + j] = v;
    }
  }
}

// ---------------- causal depthwise conv (DC=4) + SiLU ----------------
// xz: [B,L,2*DI] (x_in = first DI cols), out xc: [B,L,DI]
__global__ void conv_silu_kernel(const float* __restrict__ xz,
                                 const float* __restrict__ cw,  // [DI,4]
                                 const float* __restrict__ cb,  // [DI]
                                 float* __restrict__ xc) {
  size_t idx = (size_t)blockIdx.x * blockDim.x + threadIdx.x;
  if (idx >= (size_t)B * L * DI) return;
  int c = (int)(idx % DI);
  int l = (int)((idx / DI) % L);
  int b = (int)(idx / ((size_t)DI * L));
  const float* xp = xz + (size_t)b * L * (2 * DI) + c;
  float w0 = cw[c * 4 + 0], w1 = cw[c * 4 + 1], w2 = cw[c * 4 + 2], w3 = cw[c * 4 + 3];
  float acc = cb[c];
  if (l >= 3) acc += w0 * xp[(size_t)(l - 3) * (2 * DI)];
  if (l >= 2) acc += w1 * xp[(size_t)(l - 2) * (2 * DI)];
  if (l >= 1) acc += w2 * xp[(size_t)(l - 1) * (2 * DI)];
  acc += w3 * xp[(size_t)l * (2 * DI)];
  xc[idx] = siluf(acc);
}

// ---------------- u[l,b,s] = INSCALE * sum_c xc[b,l,c] * A[l,c,s] ----------------
// One block per l. u layout: [L, B*DS]
__global__ __launch_bounds__(256) void u_kernel(const float* __restrict__ xc,   // [B,L,DI]
                                                const float* __restrict__ A_l,  // [L,DI,DS]
                                                float* __restrict__ u) {        // [L,B*DS]
  const int l = blockIdx.x;
  __shared__ float xs[B][DI];        // 48 KB
  __shared__ float red[16 * 16 * 8]; // 8 KB
  for (int i = threadIdx.x; i < B * DI; i += 256) {
    int b = i / DI, c = i % DI;
    xs[b][c] = xc[((size_t)b * L + l) * DI + c];
  }
  __syncthreads();
  const int s = threadIdx.x & 15;
  const int g = threadIdx.x >> 4;   // 16 groups over c
  const float* Ap = A_l + (size_t)l * DI * DS;
  float acc[B];
#pragma unroll
  for (int b = 0; b < B; ++b) acc[b] = 0.f;
  for (int c0 = 0; c0 < DI; c0 += 16) {
    float a = Ap[(size_t)(c0 + g) * DS + s];
    int c = c0 + g;
#pragma unroll
    for (int b = 0; b < B; ++b) acc[b] += xs[b][c] * a;
  }
#pragma unroll
  for (int b = 0; b < B; ++b) red[(g * 16 + s) * 8 + b] = acc[b];
  __syncthreads();
  if (threadIdx.x < 128) {
    int ss = threadIdx.x >> 3;
    int b  = threadIdx.x & 7;
    float sum = 0.f;
#pragma unroll
    for (int gg = 0; gg < 16; ++gg) sum += red[(gg * 16 + ss) * 8 + b];
    u[(size_t)l * (B * DS) + b * DS + ss] = INSCALE * sum;
  }
}

// ---------------- sequential scan over l (128 independent streams) ----------------
__global__ void scan_kernel(const float* __restrict__ u, float* __restrict__ hs) {
  const int t = threadIdx.x;  // 0..127 = b*16+s
  float h = 0.f;
#pragma unroll 4
  for (int l = 0; l < L; ++l) {
    h = DECAY * h + u[(size_t)l * (B * DS) + t];
    hs[(size_t)l * (B * DS) + t] = h;
  }
}

// ---------------- x_ssm + gating: y[b,l,c] = (sum_s hs[l,b,s]*Bm[l,s,c]) * silu(z) ----------------
__global__ __launch_bounds__(256) void xssm_kernel(const float* __restrict__ hs,   // [L,B*DS]
                                                   const float* __restrict__ B_l,  // [L,DS,DI]
                                                   const float* __restrict__ xz,   // [B,L,2*DI]
                                                   float* __restrict__ y) {        // [B,L,DI]
  const int l = blockIdx.x;
  __shared__ float hsl[B * DS];
  if (threadIdx.x < B * DS) hsl[threadIdx.x] = hs[(size_t)l * (B * DS) + threadIdx.x];
  __syncthreads();
  const float* Bp = B_l + (size_t)l * DS * DI;
  for (int c = threadIdx.x; c < DI; c += 256) {
    float acc[B];
#pragma unroll
    for (int b = 0; b < B; ++b) acc[b] = 0.f;
#pragma unroll
    for (int s = 0; s < DS; ++s) {
      float bv = Bp[(size_t)s * DI + c];
#pragma unroll
      for (int b = 0; b < B; ++b) acc[b] += hsl[b * DS + s] * bv;
    }
#pragma unroll
    for (int b = 0; b < B; ++b) {
      float zv = xz[((size_t)b * L + l) * (2 * DI) + DI + c];
      y[((size_t)b * L + l) * DI + c] = acc[b] * siluf(zv);
    }
  }
}

// ---------------- LayerNorm over D ----------------
__global__ __launch_bounds__(256) void ln_kernel(const float* __restrict__ x,
                                                 const float* __restrict__ gam,
                                                 const float* __restrict__ bet,
                                                 float* __restrict__ out) {
  const int row = blockIdx.x;
  const int t = threadIdx.x;
  const float* xr = x + (size_t)row * D;
  float v0 = xr[t], v1 = xr[t + 256], v2 = xr[t + 512];
  float s = v0 + v1 + v2;
  __shared__ float red[4], red2[4];
  const int wid = t >> 6, lane = t & 63;
#pragma unroll
  for (int off = 32; off > 0; off >>= 1) s += __shfl_down(s, off, 64);
  if (lane == 0) red[wid] = s;
  __syncthreads();
  float mu = (red[0] + red[1] + red[2] + red[3]) * (1.0f / D);
  float d0 = v0 - mu, d1 = v1 - mu, d2 = v2 - mu;
  float q = d0 * d0 + d1 * d1 + d2 * d2;
#pragma unroll
  for (int off = 32; off > 0; off >>= 1) q += __shfl_down(q, off, 64);
  if (lane == 0) red2[wid] = q;
  __syncthreads();
  float var = (red2[0] + red2[1] + red2[2] + red2[3]) * (1.0f / D);
  float rstd = rsqrtf(var + LN_EPS);
  size_t base = (size_t)row * D;
  out[base + t]       = d0 * rstd * gam[t]       + bet[t];
  out[base + t + 256] = d1 * rstd * gam[t + 256] + bet[t + 256];
  out[base + t + 512] = d2 * rstd * gam[t + 512] + bet[t + 512];
}

extern "C" void kernel_launch(void* const* d_in, const int* in_sizes, int n_in,
                              void* d_out, int out_size, void* d_ws, size_t ws_size,
                              hipStream_t stream) {
  (void)in_sizes; (void)n_in; (void)out_size; (void)ws_size;
  const float* x   = (const float*)d_in[0];
  const float* Wi  = (const float*)d_in[1];
  const float* cw  = (const float*)d_in[2];
  const float* cb  = (const float*)d_in[3];
  const float* Wo  = (const float*)d_in[4];
  const float* gam = (const float*)d_in[5];
  const float* bet = (const float*)d_in[6];
  const float* Am  = (const float*)d_in[7];
  const float* Bm  = (const float*)d_in[8];
  float* out = (float*)d_out;

  float* buf_x  = (float*)d_ws;                       // [B*L, D]
  float* buf_xz = buf_x  + (size_t)B * L * D;         // [B*L, 2*DI]
  float* buf_xc = buf_xz + (size_t)B * L * 2 * DI;    // [B*L, DI] (also y)
  float* buf_u  = buf_xc + (size_t)B * L * DI;        // [L, B*DS]
  float* buf_hs = buf_u  + (size_t)L * B * DS;        // [L, B*DS]

  {
    int n4 = B * L * D / 4;
    copy_f4<<<(n4 + 255) / 256, 256, 0, stream>>>((const float4*)x, (float4*)buf_x, n4);
  }

  for (int layer = 0; layer < NL; ++layer) {
    const float* Wi_l = Wi + (size_t)layer * D * 2 * DI;
    const float* cw_l = cw + (size_t)layer * DI * 4;
    const float* cb_l = cb + (size_t)layer * DI;
    const float* Wo_l = Wo + (size_t)layer * DI * D;
    const float* A_l  = Am + (size_t)layer * L * DI * DS;
    const float* B_l  = Bm + (size_t)layer * L * DS * DI;

    // xz = x @ Wi   [8192,768]x[768,3072]
    sgemm<128, 128, 8, 8, 8, false>
        <<<dim3(2 * DI / 128, B * L / 128), 256, 0, stream>>>(buf_x, Wi_l, buf_xz, B * L, 2 * DI, D);

    // xc = silu(causal dwconv(x_in))
    {
      size_t n = (size_t)B * L * DI;
      conv_silu_kernel<<<(unsigned)((n + 255) / 256), 256, 0, stream>>>(buf_xz, cw_l, cb_l, buf_xc);
    }

    // u = 0.1 * xc @ A_l (per l)
    u_kernel<<<L, 256, 0, stream>>>(buf_xc, A_l, buf_u);

    // hs = scan(u)
    scan_kernel<<<1, 128, 0, stream>>>(buf_u, buf_hs);

    // y = (hs @ B_l) * silu(z)   (into buf_xc)
    xssm_kernel<<<L, 256, 0, stream>>>(buf_hs, B_l, buf_xz, buf_xc);

    // x += y @ Wo   [8192,1536]x[1536,768]
    sgemm<64, 128, 8, 4, 8, true>
        <<<dim3(D / 128, B * L / 64), 256, 0, stream>>>(buf_xc, Wo_l, buf_x, B * L, D, DI);
  }

  ln_kernel<<<B * L, 256, 0, stream>>>(buf_x, gam, bet, out);
}

// Round 2
// 970.807 us; speedup vs baseline: 2.2629x; 2.2629x over previous
//
#include <hip/hip_runtime.h>
#include <cstddef>
#include <cstdint>

// Problem constants
constexpr int B  = 8;
constexpr int L  = 1024;
constexpr int D  = 768;
constexpr int DI = 1536;
constexpr int DS = 16;
constexpr int NL = 2;
constexpr float DECAY   = 0.9f;
constexpr float INSCALE = 0.1f;
constexpr float LN_EPS  = 1e-5f;

typedef __attribute__((ext_vector_type(8))) short bf16x8;
typedef __attribute__((ext_vector_type(4))) float f32x4;

typedef __attribute__((address_space(3))) uint32_t       lds_u32;
typedef const __attribute__((address_space(1))) uint32_t glb_u32;

__device__ __forceinline__ float siluf(float v) { return v / (1.0f + expf(-v)); }

// f32 -> bf16 (round to nearest even)
__device__ __forceinline__ short f2bf(float f) {
  uint32_t u = __float_as_uint(f);
  u += 0x7fff + ((u >> 16) & 1);
  return (short)(u >> 16);
}

__device__ __forceinline__ void load_lds16(const short* g, short* l) {
  __builtin_amdgcn_global_load_lds((glb_u32*)g, (lds_u32*)l, 16, 0, 0);
}

// ---------------- convert input x: f32 copy + bf16 copy ----------------
__global__ void convert_x_kernel(const float* __restrict__ x, float* __restrict__ xf,
                                 short* __restrict__ xb, int n4) {
  int i = blockIdx.x * blockDim.x + threadIdx.x;
  if (i >= n4) return;
  float4 v = ((const float4*)x)[i];
  ((float4*)xf)[i] = v;
  short4 s;
  s.x = f2bf(v.x); s.y = f2bf(v.y); s.z = f2bf(v.z); s.w = f2bf(v.w);
  ((short4*)xb)[i] = s;
}

// ---------------- W[K,N] f32 -> Wt[N,K] bf16 ----------------
__global__ __launch_bounds__(256) void transpose_bf16_kernel(const float* __restrict__ W,
                                                             short* __restrict__ Wt,
                                                             int K, int N) {
  __shared__ float t[32][33];
  const int n0 = blockIdx.x * 32, k0 = blockIdx.y * 32;
  const int tx = threadIdx.x & 31, ty = threadIdx.x >> 5;  // ty 0..7
#pragma unroll
  for (int r = ty; r < 32; r += 8) t[r][tx] = W[(size_t)(k0 + r) * N + n0 + tx];
  __syncthreads();
#pragma unroll
  for (int r = ty; r < 32; r += 8) Wt[(size_t)(n0 + r) * K + k0 + tx] = f2bf(t[tx][r]);
}

// ---------------- bf16 MFMA GEMM: C[M,N] = A[M,K] @ Bt[N,K]^T ----------------
// m97 structure: 128x128 tile, BK=32, 4 waves each computing 64x64,
// global_load_lds width=16 staging, 16x16x32 bf16 MFMA, f32 accum.
// ACCUM: C += result (residual). WRITE_BF16: also write bf16 copy to Cb.
template<bool ACCUM, bool WRITE_BF16>
__global__ __launch_bounds__(256) void gemm_bt(const short* __restrict__ A,
                                               const short* __restrict__ Bt,
                                               float* __restrict__ C,
                                               short* __restrict__ Cb,
                                               int M, int N, int K) {
  __shared__ short As[128 * 32];
  __shared__ short Bs[128 * 32];
  const int tid  = threadIdx.x;
  const int lane = tid & 63;
  const int w    = tid >> 6;        // wave 0..3
  const int wm   = w >> 1;          // wave row tile (0..1)
  const int wn   = w & 1;           // wave col tile (0..1)
  const int bm   = blockIdx.y * 128;
  const int bn   = blockIdx.x * 128;

  // staging: each wave stages 2 segments (16 rows each) of A and of Bt.
  // segment s covers rows s*16..s*16+15; lane i -> row s*16 + i/4, k-chunk (i%4)*8
  const int seg0 = w * 2;
  const int rS0  = seg0 * 16 + (lane >> 2);
  const int rS1  = rS0 + 16;
  const int kc   = (lane & 3) * 8;

  const short* gA0 = A  + (size_t)(bm + rS0) * K + kc;
  const short* gA1 = A  + (size_t)(bm + rS1) * K + kc;
  const short* gB0 = Bt + (size_t)(bn + rS0) * K + kc;
  const short* gB1 = Bt + (size_t)(bn + rS1) * K + kc;
  short* lA0 = &As[(size_t)seg0 * 512];
  short* lA1 = &As[(size_t)(seg0 + 1) * 512];
  short* lB0 = &Bs[(size_t)seg0 * 512];
  short* lB1 = &Bs[(size_t)(seg0 + 1) * 512];

  f32x4 acc[4][4];
#pragma unroll
  for (int i = 0; i < 4; ++i)
#pragma unroll
    for (int j = 0; j < 4; ++j) acc[i][j] = (f32x4)(0.f);

  const int fr = lane & 15;         // row within 16x16 fragment
  const int fk = (lane >> 4) * 8;   // k offset within BK=32

  for (int k0 = 0; k0 < K; k0 += 32) {
    __syncthreads();                // previous compute done before overwrite
    load_lds16(gA0 + k0, lA0);
    load_lds16(gA1 + k0, lA1);
    load_lds16(gB0 + k0, lB0);
    load_lds16(gB1 + k0, lB1);
    __syncthreads();                // staged data visible (vmcnt drained)

    bf16x8 af[4], bfr[4];
#pragma unroll
    for (int i = 0; i < 4; ++i)
      af[i] = *(const bf16x8*)&As[(size_t)(wm * 64 + i * 16 + fr) * 32 + fk];
#pragma unroll
    for (int j = 0; j < 4; ++j)
      bfr[j] = *(const bf16x8*)&Bs[(size_t)(wn * 64 + j * 16 + fr) * 32 + fk];
#pragma unroll
    for (int i = 0; i < 4; ++i)
#pragma unroll
      for (int j = 0; j < 4; ++j)
        acc[i][j] = __builtin_amdgcn_mfma_f32_16x16x32_bf16(af[i], bfr[j], acc[i][j], 0, 0, 0);
  }

  // epilogue: C/D frag mapping col=lane&15, row=(lane>>4)*4+r
  const int orow = (lane >> 4) * 4;
  const int ocol = lane & 15;
#pragma unroll
  for (int i = 0; i < 4; ++i) {
#pragma unroll
    for (int r = 0; r < 4; ++r) {
      const size_t row = (size_t)(bm + wm * 64 + i * 16 + orow + r);
      float* cp = C + row * N + bn + wn * 64 + ocol;
      short* cbp = Cb + row * N + bn + wn * 64 + ocol;
#pragma unroll
      for (int j = 0; j < 4; ++j) {
        float v = acc[i][j][r];
        if (ACCUM) v += cp[j * 16];
        cp[j * 16] = v;
        if (WRITE_BF16) cbp[j * 16] = f2bf(v);
      }
    }
  }
}

// ---------------- causal depthwise conv (DC=4) + SiLU ----------------
__global__ void conv_silu_kernel(const float* __restrict__ xz,
                                 const float* __restrict__ cw,  // [DI,4]
                                 const float* __restrict__ cb,  // [DI]
                                 float* __restrict__ xc) {
  size_t idx = (size_t)blockIdx.x * blockDim.x + threadIdx.x;
  if (idx >= (size_t)B * L * DI) return;
  int c = (int)(idx % DI);
  int l = (int)((idx / DI) % L);
  int b = (int)(idx / ((size_t)DI * L));
  const float* xp = xz + (size_t)b * L * (2 * DI) + c;
  float w0 = cw[c * 4 + 0], w1 = cw[c * 4 + 1], w2 = cw[c * 4 + 2], w3 = cw[c * 4 + 3];
  float acc = cb[c];
  if (l >= 3) acc += w0 * xp[(size_t)(l - 3) * (2 * DI)];
  if (l >= 2) acc += w1 * xp[(size_t)(l - 2) * (2 * DI)];
  if (l >= 1) acc += w2 * xp[(size_t)(l - 1) * (2 * DI)];
  acc += w3 * xp[(size_t)l * (2 * DI)];
  xc[idx] = siluf(acc);
}

// ---------------- u[l,b,s] = INSCALE * sum_c xc[b,l,c] * A[l,c,s] ----------------
__global__ __launch_bounds__(256) void u_kernel(const float* __restrict__ xc,   // [B,L,DI]
                                                const float* __restrict__ A_l,  // [L,DI,DS]
                                                float* __restrict__ u) {        // [L,B*DS]
  const int l = blockIdx.x;
  __shared__ float xs[B][DI];
  __shared__ float red[16 * 16 * 8];
  for (int i = threadIdx.x; i < B * DI; i += 256) {
    int b = i / DI, c = i % DI;
    xs[b][c] = xc[((size_t)b * L + l) * DI + c];
  }
  __syncthreads();
  const int s = threadIdx.x & 15;
  const int g = threadIdx.x >> 4;
  const float* Ap = A_l + (size_t)l * DI * DS;
  float acc[B];
#pragma unroll
  for (int b = 0; b < B; ++b) acc[b] = 0.f;
  for (int c0 = 0; c0 < DI; c0 += 16) {
    float a = Ap[(size_t)(c0 + g) * DS + s];
    int c = c0 + g;
#pragma unroll
    for (int b = 0; b < B; ++b) acc[b] += xs[b][c] * a;
  }
#pragma unroll
  for (int b = 0; b < B; ++b) red[(g * 16 + s) * 8 + b] = acc[b];
  __syncthreads();
  if (threadIdx.x < 128) {
    int ss = threadIdx.x >> 3;
    int b  = threadIdx.x & 7;
    float sum = 0.f;
#pragma unroll
    for (int gg = 0; gg < 16; ++gg) sum += red[(gg * 16 + ss) * 8 + b];
    u[(size_t)l * (B * DS) + b * DS + ss] = INSCALE * sum;
  }
}

// ---------------- sequential scan over l ----------------
__global__ void scan_kernel(const float* __restrict__ u, float* __restrict__ hs) {
  const int t = threadIdx.x;  // 0..127 = b*16+s
  float h = 0.f;
#pragma unroll 4
  for (int l = 0; l < L; ++l) {
    h = DECAY * h + u[(size_t)l * (B * DS) + t];
    hs[(size_t)l * (B * DS) + t] = h;
  }
}

// ---------------- y[b,l,c] = (sum_s hs[l,b,s]*Bm[l,s,c]) * silu(z), bf16 out ----------------
__global__ __launch_bounds__(256) void xssm_kernel(const float* __restrict__ hs,   // [L,B*DS]
                                                   const float* __restrict__ B_l,  // [L,DS,DI]
                                                   const float* __restrict__ xz,   // [B,L,2*DI]
                                                   short* __restrict__ y) {        // [B,L,DI] bf16
  const int l = blockIdx.x;
  __shared__ float hsl[B * DS];
  if (threadIdx.x < B * DS) hsl[threadIdx.x] = hs[(size_t)l * (B * DS) + threadIdx.x];
  __syncthreads();
  const float* Bp = B_l + (size_t)l * DS * DI;
  for (int c = threadIdx.x; c < DI; c += 256) {
    float acc[B];
#pragma unroll
    for (int b = 0; b < B; ++b) acc[b] = 0.f;
#pragma unroll
    for (int s = 0; s < DS; ++s) {
      float bv = Bp[(size_t)s * DI + c];
#pragma unroll
      for (int b = 0; b < B; ++b) acc[b] += hsl[b * DS + s] * bv;
    }
#pragma unroll
    for (int b = 0; b < B; ++b) {
      float zv = xz[((size_t)b * L + l) * (2 * DI) + DI + c];
      y[((size_t)b * L + l) * DI + c] = f2bf(acc[b] * siluf(zv));
    }
  }
}

// ---------------- LayerNorm over D ----------------
__global__ __launch_bounds__(256) void ln_kernel(const float* __restrict__ x,
                                                 const float* __restrict__ gam,
                                                 const float* __restrict__ bet,
                                                 float* __restrict__ out) {
  const int row = blockIdx.x;
  const int t = threadIdx.x;
  const float* xr = x + (size_t)row * D;
  float v0 = xr[t], v1 = xr[t + 256], v2 = xr[t + 512];
  float s = v0 + v1 + v2;
  __shared__ float red[4], red2[4];
  const int wid = t >> 6, lane = t & 63;
#pragma unroll
  for (int off = 32; off > 0; off >>= 1) s += __shfl_down(s, off, 64);
  if (lane == 0) red[wid] = s;
  __syncthreads();
  float mu = (red[0] + red[1] + red[2] + red[3]) * (1.0f / D);
  float d0 = v0 - mu, d1 = v1 - mu, d2 = v2 - mu;
  float q = d0 * d0 + d1 * d1 + d2 * d2;
#pragma unroll
  for (int off = 32; off > 0; off >>= 1) q += __shfl_down(q, off, 64);
  if (lane == 0) red2[wid] = q;
  __syncthreads();
  float var = (red2[0] + red2[1] + red2[2] + red2[3]) * (1.0f / D);
  float rstd = rsqrtf(var + LN_EPS);
  size_t base = (size_t)row * D;
  out[base + t]       = d0 * rstd * gam[t]       + bet[t];
  out[base + t + 256] = d1 * rstd * gam[t + 256] + bet[t + 256];
  out[base + t + 512] = d2 * rstd * gam[t + 512] + bet[t + 512];
}

extern "C" void kernel_launch(void* const* d_in, const int* in_sizes, int n_in,
                              void* d_out, int out_size, void* d_ws, size_t ws_size,
                              hipStream_t stream) {
  (void)in_sizes; (void)n_in; (void)out_size; (void)ws_size;
  const float* x   = (const float*)d_in[0];
  const float* Wi  = (const float*)d_in[1];
  const float* cw  = (const float*)d_in[2];
  const float* cb  = (const float*)d_in[3];
  const float* Wo  = (const float*)d_in[4];
  const float* gam = (const float*)d_in[5];
  const float* bet = (const float*)d_in[6];
  const float* Am  = (const float*)d_in[7];
  const float* Bm  = (const float*)d_in[8];
  float* out = (float*)d_out;

  const size_t MN = (size_t)B * L;  // 8192

  float* buf_x  = (float*)d_ws;                        // [MN, D] f32 residual
  short* buf_xb = (short*)(buf_x + MN * D);            // [MN, D] bf16 activation
  float* buf_xz = (float*)(buf_xb + MN * D);           // [MN, 2*DI] f32
  float* buf_xc = buf_xz + MN * 2 * DI;                // [MN, DI] f32 (xc), aliased below as y_bf
  float* buf_u  = buf_xc + MN * DI;                    // [L, B*DS]
  float* buf_hs = buf_u + (size_t)L * B * DS;          // [L, B*DS]
  short* Wt_i   = (short*)(buf_hs + (size_t)L * B * DS); // [NL, 2*DI, D] bf16 (W^T)
  short* Wt_o   = Wt_i + (size_t)NL * 2 * DI * D;        // [NL, D, DI]  bf16 (W^T)
  short* y_bf   = (short*)buf_xc;                      // [MN, DI] bf16 (reuses xc space)

  // prep: x -> f32 residual + bf16; weights -> bf16 transposed [N,K]
  {
    int n4 = (int)(MN * D / 4);
    convert_x_kernel<<<(n4 + 255) / 256, 256, 0, stream>>>(x, buf_x, buf_xb, n4);
  }
  for (int layer = 0; layer < NL; ++layer) {
    transpose_bf16_kernel<<<dim3(2 * DI / 32, D / 32), 256, 0, stream>>>(
        Wi + (size_t)layer * D * 2 * DI, Wt_i + (size_t)layer * 2 * DI * D, D, 2 * DI);
    transpose_bf16_kernel<<<dim3(D / 32, DI / 32), 256, 0, stream>>>(
        Wo + (size_t)layer * DI * D, Wt_o + (size_t)layer * D * DI, DI, D);
  }

  for (int layer = 0; layer < NL; ++layer) {
    const float* cw_l = cw + (size_t)layer * DI * 4;
    const float* cb_l = cb + (size_t)layer * DI;
    const float* A_l  = Am + (size_t)layer * L * DI * DS;
    const float* B_l  = Bm + (size_t)layer * L * DS * DI;
    const short* Wti_l = Wt_i + (size_t)layer * 2 * DI * D;
    const short* Wto_l = Wt_o + (size_t)layer * D * DI;

    // xz = x @ Wi   [8192,768] x [768,3072] -> f32
    gemm_bt<false, false><<<dim3(2 * DI / 128, MN / 128), 256, 0, stream>>>(
        buf_xb, Wti_l, buf_xz, nullptr, (int)MN, 2 * DI, D);

    // xc = silu(causal dwconv(x_in))
    {
      size_t n = MN * DI;
      conv_silu_kernel<<<(unsigned)((n + 255) / 256), 256, 0, stream>>>(buf_xz, cw_l, cb_l, buf_xc);
    }

    // u = 0.1 * xc @ A_l
    u_kernel<<<L, 256, 0, stream>>>(buf_xc, A_l, buf_u);

    // hs = scan(u)
    scan_kernel<<<1, 128, 0, stream>>>(buf_u, buf_hs);

    // y = (hs @ B_l) * silu(z)  -> bf16 (overwrites xc space)
    xssm_kernel<<<L, 256, 0, stream>>>(buf_hs, B_l, buf_xz, y_bf);

    // x += y @ Wo  [8192,1536] x [1536,768]; also emit bf16 x for next layer
    gemm_bt<true, true><<<dim3(D / 128, MN / 128), 256, 0, stream>>>(
        y_bf, Wto_l, buf_x, buf_xb, (int)MN, D, DI);
  }

  ln_kernel<<<(int)MN, 256, 0, stream>>>(buf_x, gam, bet, out);
}

// Round 3
// 687.489 us; speedup vs baseline: 3.1954x; 1.4121x over previous
//
#include <hip/hip_runtime.h>
#include <cstddef>
#include <cstdint>

// Problem constants
constexpr int B  = 8;
constexpr int L  = 1024;
constexpr int D  = 768;
constexpr int DI = 1536;
constexpr int DS = 16;
constexpr int NL = 2;
constexpr float DECAY   = 0.9f;
constexpr float INSCALE = 0.1f;
constexpr float LN_EPS  = 1e-5f;

typedef __attribute__((ext_vector_type(8))) short bf16x8;
typedef __attribute__((ext_vector_type(4))) float f32x4;

typedef __attribute__((address_space(3))) uint32_t       lds_u32;
typedef const __attribute__((address_space(1))) uint32_t glb_u32;

__device__ __forceinline__ float siluf(float v) { return v / (1.0f + expf(-v)); }

// f32 -> bf16 (round to nearest even)
__device__ __forceinline__ short f2bf(float f) {
  uint32_t u = __float_as_uint(f);
  u += 0x7fff + ((u >> 16) & 1);
  return (short)(u >> 16);
}

__device__ __forceinline__ void load_lds16(const short* g, short* l) {
  __builtin_amdgcn_global_load_lds((glb_u32*)g, (lds_u32*)l, 16, 0, 0);
}

// ---------------- convert input x: f32 copy + bf16 copy ----------------
__global__ void convert_x_kernel(const float* __restrict__ x, float* __restrict__ xf,
                                 short* __restrict__ xb, int n4) {
  int i = blockIdx.x * blockDim.x + threadIdx.x;
  if (i >= n4) return;
  float4 v = ((const float4*)x)[i];
  ((float4*)xf)[i] = v;
  short4 s;
  s.x = f2bf(v.x); s.y = f2bf(v.y); s.z = f2bf(v.z); s.w = f2bf(v.w);
  ((short4*)xb)[i] = s;
}

// ---------------- W[K,N] f32 -> Wt[N,K] bf16 ----------------
__global__ __launch_bounds__(256) void transpose_bf16_kernel(const float* __restrict__ W,
                                                             short* __restrict__ Wt,
                                                             int K, int N) {
  __shared__ float t[32][33];
  const int n0 = blockIdx.x * 32, k0 = blockIdx.y * 32;
  const int tx = threadIdx.x & 31, ty = threadIdx.x >> 5;  // ty 0..7
#pragma unroll
  for (int r = ty; r < 32; r += 8) t[r][tx] = W[(size_t)(k0 + r) * N + n0 + tx];
  __syncthreads();
#pragma unroll
  for (int r = ty; r < 32; r += 8) Wt[(size_t)(n0 + r) * K + k0 + tx] = f2bf(t[tx][r]);
}

// ---------------- bf16 MFMA GEMM: C[M,N] = A[M,K] @ Bt[N,K]^T ----------------
template<bool ACCUM, bool WRITE_BF16>
__global__ __launch_bounds__(256) void gemm_bt(const short* __restrict__ A,
                                               const short* __restrict__ Bt,
                                               float* __restrict__ C,
                                               short* __restrict__ Cb,
                                               int M, int N, int K) {
  __shared__ short As[128 * 32];
  __shared__ short Bs[128 * 32];
  const int tid  = threadIdx.x;
  const int lane = tid & 63;
  const int w    = tid >> 6;
  const int wm   = w >> 1;
  const int wn   = w & 1;
  const int bm   = blockIdx.y * 128;
  const int bn   = blockIdx.x * 128;

  const int seg0 = w * 2;
  const int rS0  = seg0 * 16 + (lane >> 2);
  const int rS1  = rS0 + 16;
  const int kc   = (lane & 3) * 8;

  const short* gA0 = A  + (size_t)(bm + rS0) * K + kc;
  const short* gA1 = A  + (size_t)(bm + rS1) * K + kc;
  const short* gB0 = Bt + (size_t)(bn + rS0) * K + kc;
  const short* gB1 = Bt + (size_t)(bn + rS1) * K + kc;
  short* lA0 = &As[(size_t)seg0 * 512];
  short* lA1 = &As[(size_t)(seg0 + 1) * 512];
  short* lB0 = &Bs[(size_t)seg0 * 512];
  short* lB1 = &Bs[(size_t)(seg0 + 1) * 512];

  f32x4 acc[4][4];
#pragma unroll
  for (int i = 0; i < 4; ++i)
#pragma unroll
    for (int j = 0; j < 4; ++j) acc[i][j] = (f32x4)(0.f);

  const int fr = lane & 15;
  const int fk = (lane >> 4) * 8;

  for (int k0 = 0; k0 < K; k0 += 32) {
    __syncthreads();
    load_lds16(gA0 + k0, lA0);
    load_lds16(gA1 + k0, lA1);
    load_lds16(gB0 + k0, lB0);
    load_lds16(gB1 + k0, lB1);
    __syncthreads();

    bf16x8 af[4], bfr[4];
#pragma unroll
    for (int i = 0; i < 4; ++i)
      af[i] = *(const bf16x8*)&As[(size_t)(wm * 64 + i * 16 + fr) * 32 + fk];
#pragma unroll
    for (int j = 0; j < 4; ++j)
      bfr[j] = *(const bf16x8*)&Bs[(size_t)(wn * 64 + j * 16 + fr) * 32 + fk];
#pragma unroll
    for (int i = 0; i < 4; ++i)
#pragma unroll
      for (int j = 0; j < 4; ++j)
        acc[i][j] = __builtin_amdgcn_mfma_f32_16x16x32_bf16(af[i], bfr[j], acc[i][j], 0, 0, 0);
  }

  const int orow = (lane >> 4) * 4;
  const int ocol = lane & 15;
#pragma unroll
  for (int i = 0; i < 4; ++i) {
#pragma unroll
    for (int r = 0; r < 4; ++r) {
      const size_t row = (size_t)(bm + wm * 64 + i * 16 + orow + r);
      float* cp = C + row * N + bn + wn * 64 + ocol;
      short* cbp = Cb + row * N + bn + wn * 64 + ocol;
#pragma unroll
      for (int j = 0; j < 4; ++j) {
        float v = acc[i][j][r];
        if (ACCUM) v += cp[j * 16];
        cp[j * 16] = v;
        if (WRITE_BF16) cbp[j * 16] = f2bf(v);
      }
    }
  }
}

// ---------------- causal depthwise conv (DC=4) + SiLU, float4 ----------------
__global__ void conv_silu_kernel(const float* __restrict__ xz,
                                 const float* __restrict__ cw,  // [DI,4]
                                 const float* __restrict__ cb,  // [DI]
                                 float* __restrict__ xc) {
  int i = blockIdx.x * blockDim.x + threadIdx.x;  // over B*L*DI/4
  if (i >= B * L * DI / 4) return;
  const int c  = (i % (DI / 4)) * 4;
  const int l  = (i / (DI / 4)) % L;
  const int b  = i / ((DI / 4) * L);
  const float* xp = xz + (size_t)b * L * (2 * DI) + c;
  // taps for 4 consecutive channels: cw[(c+j)*4 + k]
  float4 q0 = *(const float4*)&cw[(c + 0) * 4];
  float4 q1 = *(const float4*)&cw[(c + 1) * 4];
  float4 q2 = *(const float4*)&cw[(c + 2) * 4];
  float4 q3 = *(const float4*)&cw[(c + 3) * 4];
  float4 acc = *(const float4*)&cb[c];
#pragma unroll
  for (int k = 0; k < 4; ++k) {
    int lk = l - 3 + k;
    if (lk >= 0) {
      float4 xv = *(const float4*)&xp[(size_t)lk * (2 * DI)];
      float w0 = (&q0.x)[k], w1 = (&q1.x)[k], w2 = (&q2.x)[k], w3 = (&q3.x)[k];
      acc.x += w0 * xv.x; acc.y += w1 * xv.y; acc.z += w2 * xv.z; acc.w += w3 * xv.w;
    }
  }
  acc.x = siluf(acc.x); acc.y = siluf(acc.y); acc.z = siluf(acc.z); acc.w = siluf(acc.w);
  *(float4*)&xc[((size_t)b * L + l) * DI + c] = acc;
}

// ---------------- u[l,b,s] = INSCALE * sum_c xc[b,l,c] * A[l,c,s] ----------------
// One block per l, 256 threads. Thread (cg=t>>2, s4=t&3) accumulates
// A[c, s4*4..s4*4+3] float4 over c in {c0+cg}. Reduction via padded LDS.
__global__ __launch_bounds__(256) void u_kernel(const float* __restrict__ xc,   // [B,L,DI]
                                                const float* __restrict__ A_l,  // [L,DI,DS]
                                                float* __restrict__ u) {        // [L,B*DS]
  const int l = blockIdx.x;
  __shared__ float smem[B * DI];  // 48 KB: xc staging, then reused as reduction buf
  for (int i = threadIdx.x; i < B * DI / 4; i += 256) {
    int b = i / (DI / 4), c4 = i % (DI / 4);
    ((float4*)smem)[i] = *(const float4*)&xc[((size_t)b * L + l) * DI + c4 * 4];
    (void)b;
  }
  __syncthreads();

  const int s4 = threadIdx.x & 3;    // s quarter (4 s values)
  const int cg = threadIdx.x >> 2;   // 0..63
  const float* Ap = A_l + (size_t)l * DI * DS + s4 * 4;

  float4 acc[B];
#pragma unroll
  for (int b = 0; b < B; ++b) acc[b] = make_float4(0.f, 0.f, 0.f, 0.f);

#pragma unroll 4
  for (int c0 = 0; c0 < DI; c0 += 64) {
    const int c = c0 + cg;
    float4 a4 = *(const float4*)&Ap[(size_t)c * DS];
#pragma unroll
    for (int b = 0; b < B; ++b) {
      float xv = smem[b * DI + c];
      acc[b].x += xv * a4.x; acc[b].y += xv * a4.y;
      acc[b].z += xv * a4.z; acc[b].w += xv * a4.w;
    }
  }

  __syncthreads();  // done reading xc staging; reuse smem as red[128][65]
  float* red = smem;
#pragma unroll
  for (int b = 0; b < B; ++b) {
#pragma unroll
    for (int j = 0; j < 4; ++j) {
      int o = b * 16 + s4 * 4 + j;
      red[o * 65 + cg] = (&acc[b].x)[j];
    }
  }
  __syncthreads();
  if (threadIdx.x < 128) {
    const int o = threadIdx.x;
    float sum = 0.f;
#pragma unroll 8
    for (int g = 0; g < 64; ++g) sum += red[o * 65 + g];
    u[(size_t)l * (B * DS) + o] = INSCALE * sum;
  }
}

// ---------------- truncated-lookback scan ----------------
// h_t = 0.9 h_{t-1} + u_t. Block k emits l in [64k, 64k+64), warming up from
// max(0, 64k-320): 0.9^320 ~ 2e-15 -> exact to f32 precision.
constexpr int SCAN_CH = 64;
constexpr int SCAN_W  = 320;
__global__ void scan_kernel(const float* __restrict__ u, float* __restrict__ hs) {
  const int t  = threadIdx.x;              // 0..127
  const int l1 = blockIdx.x * SCAN_CH;
  int l0 = l1 - SCAN_W; if (l0 < 0) l0 = 0;
  float h = 0.f;
  for (int l = l0; l < l1; ++l)
    h = DECAY * h + u[(size_t)l * (B * DS) + t];
#pragma unroll 4
  for (int l = l1; l < l1 + SCAN_CH; ++l) {
    h = DECAY * h + u[(size_t)l * (B * DS) + t];
    hs[(size_t)l * (B * DS) + t] = h;
  }
}

// ---------------- y[b,l,c] = (sum_s hs[l,b,s]*Bm[l,s,c]) * silu(z), bf16 out ----------------
// grid (L, 3), 128 threads; each thread owns 4 consecutive c.
__global__ __launch_bounds__(128) void xssm_kernel(const float* __restrict__ hs,   // [L,B*DS]
                                                   const float* __restrict__ B_l,  // [L,DS,DI]
                                                   const float* __restrict__ xz,   // [B,L,2*DI]
                                                   short* __restrict__ y) {        // [B,L,DI] bf16
  const int l = blockIdx.x;
  const int c = (blockIdx.y * 128 + threadIdx.x) * 4;
  __shared__ float hsl[B * DS];
  if (threadIdx.x < B * DS) hsl[threadIdx.x] = hs[(size_t)l * (B * DS) + threadIdx.x];
  __syncthreads();
  const float* Bp = B_l + (size_t)l * DS * DI + c;

  float4 acc[B];
#pragma unroll
  for (int b = 0; b < B; ++b) acc[b] = make_float4(0.f, 0.f, 0.f, 0.f);
#pragma unroll
  for (int s = 0; s < DS; ++s) {
    float4 bv = *(const float4*)&Bp[(size_t)s * DI];
#pragma unroll
    for (int b = 0; b < B; ++b) {
      float h = hsl[b * DS + s];
      acc[b].x += h * bv.x; acc[b].y += h * bv.y;
      acc[b].z += h * bv.z; acc[b].w += h * bv.w;
    }
  }
#pragma unroll
  for (int b = 0; b < B; ++b) {
    float4 zv = *(const float4*)&xz[((size_t)b * L + l) * (2 * DI) + DI + c];
    short4 o;
    o.x = f2bf(acc[b].x * siluf(zv.x));
    o.y = f2bf(acc[b].y * siluf(zv.y));
    o.z = f2bf(acc[b].z * siluf(zv.z));
    o.w = f2bf(acc[b].w * siluf(zv.w));
    *(short4*)&y[((size_t)b * L + l) * DI + c] = o;
  }
}

// ---------------- LayerNorm over D ----------------
__global__ __launch_bounds__(256) void ln_kernel(const float* __restrict__ x,
                                                 const float* __restrict__ gam,
                                                 const float* __restrict__ bet,
                                                 float* __restrict__ out) {
  const int row = blockIdx.x;
  const int t = threadIdx.x;
  const float* xr = x + (size_t)row * D;
  float v0 = xr[t], v1 = xr[t + 256], v2 = xr[t + 512];
  float s = v0 + v1 + v2;
  __shared__ float red[4], red2[4];
  const int wid = t >> 6, lane = t & 63;
#pragma unroll
  for (int off = 32; off > 0; off >>= 1) s += __shfl_down(s, off, 64);
  if (lane == 0) red[wid] = s;
  __syncthreads();
  float mu = (red[0] + red[1] + red[2] + red[3]) * (1.0f / D);
  float d0 = v0 - mu, d1 = v1 - mu, d2 = v2 - mu;
  float q = d0 * d0 + d1 * d1 + d2 * d2;
#pragma unroll
  for (int off = 32; off > 0; off >>= 1) q += __shfl_down(q, off, 64);
  if (lane == 0) red2[wid] = q;
  __syncthreads();
  float var = (red2[0] + red2[1] + red2[2] + red2[3]) * (1.0f / D);
  float rstd = rsqrtf(var + LN_EPS);
  size_t base = (size_t)row * D;
  out[base + t]       = d0 * rstd * gam[t]       + bet[t];
  out[base + t + 256] = d1 * rstd * gam[t + 256] + bet[t + 256];
  out[base + t + 512] = d2 * rstd * gam[t + 512] + bet[t + 512];
}

extern "C" void kernel_launch(void* const* d_in, const int* in_sizes, int n_in,
                              void* d_out, int out_size, void* d_ws, size_t ws_size,
                              hipStream_t stream) {
  (void)in_sizes; (void)n_in; (void)out_size; (void)ws_size;
  const float* x   = (const float*)d_in[0];
  const float* Wi  = (const float*)d_in[1];
  const float* cw  = (const float*)d_in[2];
  const float* cb  = (const float*)d_in[3];
  const float* Wo  = (const float*)d_in[4];
  const float* gam = (const float*)d_in[5];
  const float* bet = (const float*)d_in[6];
  const float* Am  = (const float*)d_in[7];
  const float* Bm  = (const float*)d_in[8];
  float* out = (float*)d_out;

  const size_t MN = (size_t)B * L;  // 8192

  float* buf_x  = (float*)d_ws;                          // [MN, D] f32 residual
  short* buf_xb = (short*)(buf_x + MN * D);              // [MN, D] bf16
  float* buf_xz = (float*)(buf_xb + MN * D);             // [MN, 2*DI] f32
  float* buf_xc = buf_xz + MN * 2 * DI;                  // [MN, DI] f32 (xc) / y bf16
  float* buf_u  = buf_xc + MN * DI;                      // [L, B*DS]
  float* buf_hs = buf_u + (size_t)L * B * DS;            // [L, B*DS]
  short* Wt_i   = (short*)(buf_hs + (size_t)L * B * DS); // [NL, 2*DI, D] bf16
  short* Wt_o   = Wt_i + (size_t)NL * 2 * DI * D;        // [NL, D, DI]  bf16
  short* y_bf   = (short*)buf_xc;

  {
    int n4 = (int)(MN * D / 4);
    convert_x_kernel<<<(n4 + 255) / 256, 256, 0, stream>>>(x, buf_x, buf_xb, n4);
  }
  for (int layer = 0; layer < NL; ++layer) {
    transpose_bf16_kernel<<<dim3(2 * DI / 32, D / 32), 256, 0, stream>>>(
        Wi + (size_t)layer * D * 2 * DI, Wt_i + (size_t)layer * 2 * DI * D, D, 2 * DI);
    transpose_bf16_kernel<<<dim3(D / 32, DI / 32), 256, 0, stream>>>(
        Wo + (size_t)layer * DI * D, Wt_o + (size_t)layer * D * DI, DI, D);
  }

  for (int layer = 0; layer < NL; ++layer) {
    const float* cw_l = cw + (size_t)layer * DI * 4;
    const float* cb_l = cb + (size_t)layer * DI;
    const float* A_l  = Am + (size_t)layer * L * DI * DS;
    const float* B_l  = Bm + (size_t)layer * L * DS * DI;
    const short* Wti_l = Wt_i + (size_t)layer * 2 * DI * D;
    const short* Wto_l = Wt_o + (size_t)layer * D * DI;

    // xz = x @ Wi   [8192,768] x [768,3072] -> f32
    gemm_bt<false, false><<<dim3(2 * DI / 128, MN / 128), 256, 0, stream>>>(
        buf_xb, Wti_l, buf_xz, nullptr, (int)MN, 2 * DI, D);

    // xc = silu(causal dwconv(x_in))
    {
      int n = (int)(MN * DI / 4);
      conv_silu_kernel<<<(n + 255) / 256, 256, 0, stream>>>(buf_xz, cw_l, cb_l, buf_xc);
    }

    // u = 0.1 * xc @ A_l
    u_kernel<<<L, 256, 0, stream>>>(buf_xc, A_l, buf_u);

    // hs = scan(u)
    scan_kernel<<<L / SCAN_CH, B * DS, 0, stream>>>(buf_u, buf_hs);

    // y = (hs @ B_l) * silu(z)  -> bf16
    xssm_kernel<<<dim3(L, 3), 128, 0, stream>>>(buf_hs, B_l, buf_xz, y_bf);

    // x += y @ Wo  [8192,1536] x [1536,768]; also emit bf16 x for next layer
    gemm_bt<true, true><<<dim3(D / 128, MN / 128), 256, 0, stream>>>(
        y_bf, Wto_l, buf_x, buf_xb, (int)MN, D, DI);
  }

  ln_kernel<<<(int)MN, 256, 0, stream>>>(buf_x, gam, bet, out);
}